// Round 16
// baseline (629.503 us; speedup 1.0000x reference)
//
#include <hip/hip_runtime.h>

// LSTM B=4096, T=512, I=1, H=64, O=1 (fp32 in/out).
// Round 16: SINGLE-WAVE MB=8, ZERO barriers, K-GROUP INTERLEAVE.
// 512 blocks x 64 thr; each wave owns 8 batches end-to-end; h in block LDS,
// intra-wave RAW via lgkmcnt only. The wave computes all 256 gate rows:
// 16 N-tiles (tile p: gate rows 16p+l16; gate type p>>2, unit group p&3),
// 2 K-chunks each = 32 MFMA/step. Source loops by unit-group k: 8 MFMA for
// tiles {k,k+4,k+8,k+12} then IMMEDIATELY the dependent cell-pair -> cells
// of group k run under group k+1's MFMAs (r15 failed by ordering all MFMAs
// first: cells unlocked at 26/32, step fully serialized, 900 idle).
// M rows: m<8 = h[batch m], m>=8 = duplicate of batch m-8 (maintained by
// extra writes) -> all acc rows valid. Lane (l16,h0): acc rows 4h0..4h0+3;
// takes r-subset {0,1} (h0<2) or {2,3} (h0>=2) -> batches B0,B0+1 with
// B0 = 4(h0&1)+2(h0>>1); units 16k+l16 -> 8 cells/lane, uniform 2-cndmask
// selects. Math = r13/r14 (exp2-prescaled W, pair-shared rcp, pk-f32,
// x*w_ih+bias as MFMA C operand). hb rows bank-skewed (+8 f16 per 4 rows):
// all h reads/writes <=2-way.
// MFMA layouts (m89-verified): A[m=lane&15][k=(lane>>4)*8+i],
// B[k=(lane>>4)*8+i][n=lane&15], D[m=(lane>>4)*4+r][n=lane&15].

#define TT  512
#define HP  72             // hb row stride (f16) before skew
#define HBSZ (16 * HP + 40)
#define SXP 12             // sh_x row stride (floats): 48B rows, 16B-aligned

#define L2E  1.4426950408889634f
#define L2E2 2.8853900817779268f

typedef _Float16 f16x8 __attribute__((ext_vector_type(8)));
typedef float    f32x4 __attribute__((ext_vector_type(4)));
typedef float    f32x2 __attribute__((ext_vector_type(2)));

#define MFMA16(a, b, c) __builtin_amdgcn_mfma_f32_16x16x32_f16((a), (b), (c), 0, 0, 0)

__device__ __forceinline__ float rcp_(float x)  { return __builtin_amdgcn_rcpf(x); }
__device__ __forceinline__ float exp2_(float x) { return __builtin_amdgcn_exp2f(x); }

__device__ __forceinline__ f16x8 cvt8s(const float4& u0, const float4& u1, float s) {
    f16x8 r;
    r[0] = (_Float16)(u0.x * s); r[1] = (_Float16)(u0.y * s);
    r[2] = (_Float16)(u0.z * s); r[3] = (_Float16)(u0.w * s);
    r[4] = (_Float16)(u1.x * s); r[5] = (_Float16)(u1.y * s);
    r[6] = (_Float16)(u1.z * s); r[7] = (_Float16)(u1.w * s);
    return r;
}

__device__ __forceinline__ int rowoff(int m) { return m * HP + (m >> 2) * 8; }

__global__ __launch_bounds__(64, 1) void lstm_w1(
    const float* __restrict__ x,      // [4096, 512]
    const float* __restrict__ w_ih,   // [256]
    const float* __restrict__ w_hh,   // [256, 64]
    const float* __restrict__ b_ih,   // [256]
    const float* __restrict__ b_hh,   // [256]
    const float* __restrict__ w_out,  // [64]
    const float* __restrict__ b_out,  // [1]
    float* __restrict__ out)          // [4096]
{
    __shared__ __align__(16) float    sh_x[TT * SXP];  // [t][batch8], 24.6 KB
    __shared__ __align__(16) _Float16 hb[HBSZ];        // skewed h rows, 2.4 KB

    const int L   = threadIdx.x;      // 0..63 (single wave)
    const int l16 = L & 15;
    const int h0  = L >> 4;           // 0..3
    const int b0  = blockIdx.x * 8;

    // ---- stage x: sh_x[t*SXP + q] = x[b0+q][t] (one-time; coalesced global) ----
    #pragma unroll
    for (int i = 0; i < 2; ++i) {
        const int t0 = 4 * (L + 64 * i);
        #pragma unroll
        for (int q = 0; q < 8; ++q) {
            float4 v = *(const float4*)(x + (size_t)(b0 + q) * TT + t0);
            sh_x[(t0 + 0) * SXP + q] = v.x;
            sh_x[(t0 + 1) * SXP + q] = v.y;
            sh_x[(t0 + 2) * SXP + q] = v.z;
            sh_x[(t0 + 3) * SXP + q] = v.w;
        }
    }
    // ---- zero h (all 16 rows incl. duplicates) ----
    for (int i = L; i < HBSZ; i += 64) hb[i] = (_Float16)0.0f;

    // ---- weights: 16 tiles, fp16-rounded + exp2-prescaled ----
    const float sc[4] = {-L2E, -L2E, L2E2, -L2E};
    f16x8 Bf[16][2];
    float wihv[16], biasv[16];
    #pragma unroll
    for (int p = 0; p < 16; ++p) {
        const int n = 16 * p + l16;
        const float s = sc[p >> 2];
        #pragma unroll
        for (int c = 0; c < 2; ++c) {
            const float* w0 = w_hh + n * 64 + 32 * c + 8 * h0;
            float4 u0 = *(const float4*)w0;
            float4 u1 = *(const float4*)(w0 + 4);
            Bf[p][c] = cvt8s(u0, u1, s);
        }
        wihv[p]  = w_ih[n] * s;
        biasv[p] = (b_ih[n] + b_hh[n]) * s;
    }

    const bool lo2 = (h0 < 2);                 // acc-element subset {0,1} vs {2,3}
    const int  B0  = 4 * (h0 & 1) + 2 * (h0 >> 1);   // lane's batches B0, B0+1
    const int  ar  = rowoff(l16) + 8 * h0;     // A-frag base (f16); +32 chunk 1
    const int  wo0 = rowoff(B0);               // batch B0 row
    const int  wo1 = rowoff(B0 + 1);           // batch B0+1 row
    const int  wd0 = rowoff(B0 + 8);           // duplicate rows
    const int  wd1 = rowoff(B0 + 9);
    const int  xq0 = 4 * (h0 & 1);             // xq = x[t][xq0..xq0+3]
    const int  xe  = 2 * (h0 >> 1);            // lane's batches within xq

    f32x2 cc[4] = {{0.f,0.f},{0.f,0.f},{0.f,0.f},{0.f,0.f}};

    // pk dual-cell update over the lane's 2 batches of one unit (r13/r14 math)
    auto pair_up = [&](f32x2 ai, f32x2 af, f32x2 ag, f32x2 ao, f32x2& c) -> f32x2 {
        f32x2 Ei = {exp2_(ai[0]), exp2_(ai[1])};
        f32x2 Ef = {exp2_(af[0]), exp2_(af[1])};
        f32x2 Eg = {exp2_(ag[0]), exp2_(ag[1])};
        f32x2 Eo = {exp2_(ao[0]), exp2_(ao[1])};
        f32x2 Di = Ei + 1.0f, Df = Ef + 1.0f, Dg = Eg + 1.0f, Do = Eo + 1.0f;
        f32x2 FG = Df * Dg, IG = Di * Dg, IF = Di * Df;
        f32x2 P  = Di * FG;
        float u  = rcp_(P[0] * P[1]);
        f32x2 inv = {u * P[1], u * P[0]};
        f32x2 si = FG * inv, sf = IG * inv;
        f32x2 tg = 1.0f - 2.0f * (IF * inv);
        c = sf * c + si * tg;
        f32x2 ca = c * L2E2;
        f32x2 Ec = {exp2_(fminf(ca[0], 30.0f)), exp2_(fminf(ca[1], 30.0f))};
        f32x2 Dc = Ec + 1.0f;
        f32x2 Q  = Do * Dc;
        float v  = rcp_(Q[0] * Q[1]);
        f32x2 iq = {v * Q[1], v * Q[0]};
        return (iq * Dc) * (1.0f - 2.0f * (iq * Do));
    };

    for (int t = 0; t < TT; ++t) {
        f16x8 A0 = *(const f16x8*)(hb + ar);
        f16x8 A1 = *(const f16x8*)(hb + ar + 32);
        f32x4 xq = *(const f32x4*)(sh_x + t * SXP + xq0);

        #pragma unroll
        for (int k = 0; k < 4; ++k) {
            // 8 MFMA for unit-group k (tiles k, k+4, k+8, k+12)
            f32x4 ag[4];
            #pragma unroll
            for (int g = 0; g < 4; ++g) {
                const int p = 4 * g + k;
                f32x4 c0 = {fmaf(xq[0], wihv[p], biasv[p]),
                            fmaf(xq[1], wihv[p], biasv[p]),
                            fmaf(xq[2], wihv[p], biasv[p]),
                            fmaf(xq[3], wihv[p], biasv[p])};
                ag[g] = MFMA16(A1, Bf[p][1], MFMA16(A0, Bf[p][0], c0));
            }
            // cell pair for unit u = 16k + l16, batches B0, B0+1
            f32x2 Ai = lo2 ? (f32x2){ag[0][0], ag[0][1]} : (f32x2){ag[0][2], ag[0][3]};
            f32x2 Af = lo2 ? (f32x2){ag[1][0], ag[1][1]} : (f32x2){ag[1][2], ag[1][3]};
            f32x2 Ag = lo2 ? (f32x2){ag[2][0], ag[2][1]} : (f32x2){ag[2][2], ag[2][3]};
            f32x2 Ao = lo2 ? (f32x2){ag[3][0], ag[3][1]} : (f32x2){ag[3][2], ag[3][3]};
            f32x2 hv = pair_up(Ai, Af, Ag, Ao, cc[k]);

            const int u = 16 * k + l16;
            _Float16 h0v = (_Float16)hv[0];
            _Float16 h1v = (_Float16)hv[1];
            hb[wo0 + u] = h0v;     // batch B0
            hb[wd0 + u] = h0v;     // dup row
            hb[wo1 + u] = h1v;     // batch B0+1
            hb[wd1 + u] = h1v;     // dup row
        }
        // no barrier: single wave; next iteration's ds_read is ordered by lgkmcnt
    }

    // ---- epilogue: out[b0+q] = h[q] . w_out + b_out ----
    const float wo = w_out[L];
    #pragma unroll
    for (int q = 0; q < 8; ++q) {
        float v = (float)hb[rowoff(q) + L] * wo;
        #pragma unroll
        for (int off = 32; off; off >>= 1) v += __shfl_down(v, off);
        if (L == 0) out[b0 + q] = v + b_out[0];
    }
}

extern "C" void kernel_launch(void* const* d_in, const int* in_sizes, int n_in,
                              void* d_out, int out_size, void* d_ws, size_t ws_size,
                              hipStream_t stream) {
    const float* x     = (const float*)d_in[0];
    const float* w_ih  = (const float*)d_in[1];
    const float* w_hh  = (const float*)d_in[2];
    const float* b_ih  = (const float*)d_in[3];
    const float* b_hh  = (const float*)d_in[4];
    const float* w_out = (const float*)d_in[5];
    const float* b_out = (const float*)d_in[6];
    float* out = (float*)d_out;

    lstm_w1<<<512, 64, 0, stream>>>(x, w_ih, w_hh, b_ih, b_hh,
                                    w_out, b_out, out);
}

// Round 17
// 306.681 us; speedup vs baseline: 2.0526x; 2.0526x over previous
//
#include <hip/hip_runtime.h>

// LSTM B=4096, T=512, I=1, H=64, O=1 (fp32 in/out).
// FINAL (= round 14, session best: 274 us steady).
// Structure: MB=8, grid=512 (2 blocks/CU, s_barrier, ~640-cyc phase stagger).
// h stored plain fp16 in even M rows (row 2q = h[batch q], odd rows zero);
// 8 MFMA/wave-step (16x16x32 f16, dense in the hi/lo-free layout); all 4
// gates of a cell colocated in one lane's acc regs (2 cells/lane, zero
// shuffles); exp2-prescaled weights (MFMA outputs ARE exp2 args);
// cross-cell shared reciprocals (6 trans/cell); packed f32x2 (v_pk_*_f32)
// cell math; x*w_ih+bias enters as the MFMA C operand, refreshed for t+1 in
// the MFMA shadow; one barrier/step; ping-pong h buffers.
// Session evidence: every structural alternative measured worse —
// dual-group blocks (r6 400us), skewed pipeline (r7 429), transposed GEMM
// (r8 375), flag-sync free-run groups (r12 341), K-packed 1-block/CU
// (r11 365), single-wave barrier-free (r15 432, r16 629). The ~600 cyc/step
// of cross-wave h-exchange latency is the structural floor of a T=512
// serial recurrence at 16 batches/CU; neither VALU (53%) nor MFMA (21%)
// pipe is saturated.
// MFMA layouts (m89-verified): A[m=lane&15][k=(lane>>4)*8+i],
// B[k=(lane>>4)*8+i][n=lane&15], D[m=(lane>>4)*4+r][n=lane&15].

#define TT   512
#define MB   8
#define HP   72            // f16 row stride (144 B): 16B-aligned, 2-way max
#define BUFE (16 * HP)     // one ping-pong buffer: 16 rows
#define SXP  10            // sh_x row stride (floats)

#define L2E  1.4426950408889634f
#define L2E2 2.8853900817779268f

typedef _Float16 f16x8 __attribute__((ext_vector_type(8)));
typedef float    f32x4 __attribute__((ext_vector_type(4)));
typedef float    f32x2 __attribute__((ext_vector_type(2)));

#define MFMA16(a, b, c) __builtin_amdgcn_mfma_f32_16x16x32_f16((a), (b), (c), 0, 0, 0)

__device__ __forceinline__ float rcp_(float x)  { return __builtin_amdgcn_rcpf(x); }
__device__ __forceinline__ float exp2_(float x) { return __builtin_amdgcn_exp2f(x); }

__device__ __forceinline__ f16x8 cvt8s(const float4& u0, const float4& u1, float s) {
    f16x8 r;
    r[0] = (_Float16)(u0.x * s); r[1] = (_Float16)(u0.y * s);
    r[2] = (_Float16)(u0.z * s); r[3] = (_Float16)(u0.w * s);
    r[4] = (_Float16)(u1.x * s); r[5] = (_Float16)(u1.y * s);
    r[6] = (_Float16)(u1.z * s); r[7] = (_Float16)(u1.w * s);
    return r;
}

__global__ __launch_bounds__(256, 2) void lstm_mfma(
    const float* __restrict__ x,      // [4096, 512]
    const float* __restrict__ w_ih,   // [256]
    const float* __restrict__ w_hh,   // [256, 64]
    const float* __restrict__ b_ih,   // [256]
    const float* __restrict__ b_hh,   // [256]
    const float* __restrict__ w_out,  // [64]
    const float* __restrict__ b_out,  // [1]
    float* __restrict__ out)          // [4096]
{
    __shared__ __align__(16) float    sh_x[TT * SXP];   // [t][m], 20 KB
    __shared__ __align__(16) _Float16 hbuf[2 * BUFE];   // 4.6 KB

    const int tid = threadIdx.x;
    const int w   = tid >> 6;    // wave 0..3 (owns N-tiles {w, w+4, w+8, w+12})
    const int L   = tid & 63;
    const int l16 = L & 15;
    const int h0  = L >> 4;      // 0..3
    const int b0  = blockIdx.x * MB;
    const int j   = 16 * w + l16;  // hidden unit col owned by this lane

    // ---- stage x: sh_x[t*SXP + m] = x[b0+m][t] (coalesced) ----
    {
        const int q = tid >> 5;   // batch 0..7
        const int l = tid & 31;
        const float* xr = x + (size_t)(b0 + q) * TT;
        #pragma unroll
        for (int i = 0; i < TT / 32; ++i)
            sh_x[(l + 32 * i) * SXP + q] = xr[l + 32 * i];
    }
    // ---- zero both h buffers (odd rows stay zero forever) ----
    for (int i = tid; i < 2 * BUFE; i += 256) hbuf[i] = (_Float16)0.0f;

    // ---- preload W_hh fragments, exp2-prescaled ----
    const float sc[4] = {-L2E, -L2E, L2E2, -L2E};
    f16x8 Bf[4][2];
    float wihv[4], biasv[4];
    #pragma unroll
    for (int s = 0; s < 4; ++s) {
        const int n = 64 * s + j;
        #pragma unroll
        for (int kt = 0; kt < 2; ++kt) {
            const float* p = w_hh + n * 64 + kt * 32 + h0 * 8;
            float4 u0 = *(const float4*)p;
            float4 u1 = *(const float4*)(p + 4);
            Bf[s][kt] = cvt8s(u0, u1, sc[s]);
        }
        wihv[s]  = w_ih[n] * sc[s];
        biasv[s] = (b_ih[n] + b_hh[n]) * sc[s];
    }

    // lane's A row m=l16: batch l16>>1 if l16 even (odd rows zero)
    const int aoff = l16 * HP + h0 * 8;   // f16 units; +32 for K-chunk 1
    // lane's cells: batches 2h0, 2h0+1 -> h rows 4h0 (cell0), 4h0+2 (cell1)
    const int xoff = 2 * h0;
    const int wr   = 4 * h0 * HP + j;

    f32x2 ccv = {0.0f, 0.0f};   // c-state of the lane's two cells

    // C-operand pipeline: rows 0,2 = x*w_ih+bias for batches 2h0, 2h0+1
    f32x4 ci[4];
    {
        const float2 x0 = *(const float2*)(sh_x + xoff);
        #pragma unroll
        for (int s = 0; s < 4; ++s) {
            ci[s][0] = fmaf(x0.x, wihv[s], biasv[s]);
            ci[s][1] = 0.0f;
            ci[s][2] = fmaf(x0.y, wihv[s], biasv[s]);
            ci[s][3] = 0.0f;
        }
    }

    __syncthreads();

    // ---- phase stagger: desync co-resident blocks by ~half a step ----
    if (((blockIdx.x >> 8) ^ blockIdx.x) & 1) {
        __builtin_amdgcn_s_sleep(10);   // ~640 cyc
    }

    auto step = [&](const _Float16* rb, _Float16* wb, int t) {
        f16x8 a0 = *(const f16x8*)(rb + aoff);
        f16x8 a1 = *(const f16x8*)(rb + aoff + 32);

        f32x4 acc[4];
        #pragma unroll
        for (int s = 0; s < 4; ++s)
            acc[s] = MFMA16(a1, Bf[s][1], MFMA16(a0, Bf[s][0], ci[s]));

        // refresh ci for t+1 in the MFMA shadow (h-independent, packed fma)
        if (t + 1 < TT) {
            const float2 xn = *(const float2*)(sh_x + (t + 1) * SXP + xoff);
            const f32x2 xnv = {xn.x, xn.y};
            #pragma unroll
            for (int s = 0; s < 4; ++s) {
                f32x2 c2 = xnv * wihv[s] + biasv[s];   // v_pk_fma_f32
                ci[s][0] = c2[0];
                ci[s][2] = c2[1];
            }
        }

        // ---- dual-cell update as float2 (v_pk_*_f32); trans stay scalar ----
        f32x2 Ei = {exp2_(acc[0][0]), exp2_(acc[0][2])};
        f32x2 Ef = {exp2_(acc[1][0]), exp2_(acc[1][2])};
        f32x2 Eg = {exp2_(acc[2][0]), exp2_(acc[2][2])};
        f32x2 Eo = {exp2_(acc[3][0]), exp2_(acc[3][2])};
        f32x2 Di = Ei + 1.0f, Df = Ef + 1.0f, Dg = Eg + 1.0f, Do = Eo + 1.0f;

        f32x2 FG = Df * Dg, IG = Di * Dg, IF = Di * Df;
        f32x2 P  = Di * FG;
        float u  = rcp_(P[0] * P[1]);
        f32x2 inv = {u * P[1], u * P[0]};

        f32x2 si = FG * inv, sf = IG * inv;
        f32x2 tg = 1.0f - 2.0f * (IF * inv);
        ccv = sf * ccv + si * tg;                       // v_pk_fma_f32

        f32x2 ca = ccv * L2E2;
        f32x2 Ec = {exp2_(fminf(ca[0], 30.0f)), exp2_(fminf(ca[1], 30.0f))};
        f32x2 Dc = Ec + 1.0f;
        f32x2 Q  = Do * Dc;
        float v  = rcp_(Q[0] * Q[1]);
        f32x2 iq = {v * Q[1], v * Q[0]};
        f32x2 hv = (iq * Dc) * (1.0f - 2.0f * (iq * Do));

        wb[wr]          = (_Float16)hv[0];   // row 4h0   (batch 2h0)
        wb[wr + 2 * HP] = (_Float16)hv[1];   // row 4h0+2 (batch 2h0+1)
        __syncthreads();
    };

    for (int t = 0; t < TT; t += 2) {
        step(hbuf,        hbuf + BUFE, t);      // read buf0, write buf1
        step(hbuf + BUFE, hbuf,        t + 1);  // read buf1, write buf0
    }

    // ---- epilogue: final h in buf0; wave w reduces batches 2w, 2w+1 ----
    const float wo = w_out[L];
    #pragma unroll
    for (int p = 0; p < 2; ++p) {
        const int q = 2 * w + p;
        float v = (float)hbuf[(2 * q) * HP + L] * wo;
        #pragma unroll
        for (int off = 32; off; off >>= 1) v += __shfl_down(v, off);
        if (L == 0) out[b0 + q] = v + b_out[0];
    }
}

extern "C" void kernel_launch(void* const* d_in, const int* in_sizes, int n_in,
                              void* d_out, int out_size, void* d_ws, size_t ws_size,
                              hipStream_t stream) {
    const float* x     = (const float*)d_in[0];
    const float* w_ih  = (const float*)d_in[1];
    const float* w_hh  = (const float*)d_in[2];
    const float* b_ih  = (const float*)d_in[3];
    const float* b_hh  = (const float*)d_in[4];
    const float* w_out = (const float*)d_in[5];
    const float* b_out = (const float*)d_in[6];
    float* out = (float*)d_out;

    lstm_mfma<<<4096 / MB, 256, 0, stream>>>(x, w_ih, w_hh, b_ih, b_hh,
                                             w_out, b_out, out);
}